// Round 4
// baseline (205.887 us; speedup 1.0000x reference)
//
#include <hip/hip_runtime.h>
#include <hip/hip_bf16.h>
#include <stdint.h>
#include <stddef.h>

#define NVOX 262144
#define CCH 128
#define BN_EPS 1e-3f

typedef __attribute__((ext_vector_type(8))) short bfrag;   // 8 bf16 = 4 VGPRs
typedef __attribute__((ext_vector_type(4))) float f4;      // 4 f32

#define AS1 __attribute__((address_space(1)))
#define AS3 __attribute__((address_space(3)))

__device__ __forceinline__ unsigned short f2bf(float f) {
  union { float f; unsigned u; } v; v.f = f;
  unsigned r = v.u + 0x7fffu + ((v.u >> 16) & 1u);   // RNE (inputs finite)
  return (unsigned short)(r >> 16);
}

__device__ __forceinline__ bfrag pack8(f4 x, f4 y) {
  bfrag r;
  r[0] = (short)f2bf(x[0]); r[1] = (short)f2bf(x[1]);
  r[2] = (short)f2bf(x[2]); r[3] = (short)f2bf(x[3]);
  r[4] = (short)f2bf(y[0]); r[5] = (short)f2bf(y[1]);
  r[6] = (short)f2bf(y[2]); r[7] = (short)f2bf(y[3]);
  return r;
}

__device__ __forceinline__ float sigmoidf_(float x) {
  return 1.f / (1.f + __expf(-x));
}

__device__ __forceinline__ float bf2f(unsigned short h) {
  union { unsigned u; float f; } v; v.u = ((unsigned)h) << 16; return v.f;
}

// ---------------------------------------------------------------------------
// Pre-swizzle W1/W2/W3 into MFMA B-fragment order, bf16:
// region r = conv*3+tap (conv: 0=W1, 1=W2, 2=W3); frag = (r*4 + kc)*8 + tile
// lane holds B[k = kc*32 + (lane>>4)*8 + e][col = tile*16 + (lane&15)]
// ---------------------------------------------------------------------------
__global__ void prep_wfrag(const float* __restrict__ W1, const float* __restrict__ W2,
                           const float* __restrict__ W3, unsigned short* __restrict__ wf) {
  const int frag = blockIdx.x;           // 0..287
  const int tile = frag & 7;
  const int kc   = (frag >> 3) & 3;
  const int tap  = (frag >> 5) % 3;
  const int conv = frag / 96;
  const float* W = (conv == 0) ? W1 : ((conv == 1) ? W2 : W3);
  const int l   = threadIdx.x;           // 0..63
  const int col = tile * 16 + (l & 15);
  const int k0  = kc * 32 + (l >> 4) * 8;
  bfrag o;
#pragma unroll
  for (int e = 0; e < 8; ++e)
    o[e] = (short)f2bf(W[(size_t)(tap * CCH + k0 + e) * CCH + col]);
  *reinterpret_cast<bfrag*>(wf + (size_t)frag * 512 + l * 8) = o;
}

// ---------------------------------------------------------------------------
// BN scale/shift tables: bn[6][128] = {sc0, sh0, sc2, sh2, sc3, sh3}
// ---------------------------------------------------------------------------
__global__ void prep_bn(const float* g0, const float* b0, const float* m0, const float* v0,
                        const float* g2, const float* b2, const float* m2, const float* v2,
                        const float* g3, const float* b3, const float* m3, const float* v3,
                        float* __restrict__ bn) {
  const int c = threadIdx.x;
  const float s0 = g0[c] * rsqrtf(v0[c] + BN_EPS);
  const float s2 = g2[c] * rsqrtf(v2[c] + BN_EPS);
  const float s3 = g3[c] * rsqrtf(v3[c] + BN_EPS);
  bn[0 * CCH + c] = s0; bn[1 * CCH + c] = b0[c] - m0[c] * s0;
  bn[2 * CCH + c] = s2; bn[3 * CCH + c] = b2[c] - m2[c] * s2;
  bn[4 * CCH + c] = s3; bn[5 * CCH + c] = b3[c] - m3[c] * s3;
}

// ---------------------------------------------------------------------------
// Features fp32 -> bf16 (row N = zeros, the sentinel row)
// ---------------------------------------------------------------------------
__global__ void prep_bf16(const float* __restrict__ feats, unsigned short* __restrict__ fbf) {
  const size_t base = ((size_t)blockIdx.x * 256 + threadIdx.x) * 8;
  const f4 x = *reinterpret_cast<const f4*>(feats + base);
  const f4 y = *reinterpret_cast<const f4*>(feats + base + 4);
  *reinterpret_cast<bfrag*>(fbf + base) = pack8(x, y);
  if (blockIdx.x == 0 && threadIdx.x < 16) {
    bfrag z = {0, 0, 0, 0, 0, 0, 0, 0};
    *reinterpret_cast<bfrag*>(fbf + (size_t)NVOX * CCH + threadIdx.x * 8) = z;
  }
}

// ---------------------------------------------------------------------------
// v4: BM=128, 512 threads (8 waves: 4 row-groups x 2 col-halves, wave=32r x 64c).
// A gathered DIRECTLY into MFMA fragment registers (global_load_dwordx4,
// double-buffered, no LDS round-trip). B triple-buffered in 96 KB LDS via
// global_load_lds -> ONE barrier per phase. Counted vmcnt(12), 3 acc sets,
// all activations in the epilogue.
// Slot order s=0..8: conv-z(W1) taps 0-2, conv-x(W3) taps 0-2, conv-y(W2) taps 0-2.
// ---------------------------------------------------------------------------
__global__ __launch_bounds__(512, 2)
void recon_v4(const unsigned short* __restrict__ fbf,
              const unsigned short* __restrict__ wfrag,
              const float* __restrict__ bn,
              const int* __restrict__ nbrz, const int* __restrict__ nbrx,
              const int* __restrict__ nbry,
              float* __restrict__ out) {
  __shared__ unsigned short Bb[3][16384];   // 96 KB, fragment-ordered

  const int tid  = threadIdx.x;
  const int lane = tid & 63;
  const int w    = tid >> 6;       // wave 0..7
  const int wr   = w >> 1;         // 32-row block 0..3
  const int wc   = w & 1;          // 64-col half 0..1
  const int row0 = blockIdx.x * 128;
  const int l15  = lane & 15;
  const int lhi  = lane >> 4;      // 0..3

  // W-fragment region per slot: slots 0-2 -> W1, 3-5 -> W3, 6-8 -> W2.
  constexpr int wfc[9] = {0, 1, 2, 6, 7, 8, 3, 4, 5};

  // ---- prologue: per-lane neighbor indices (row = l15 within each 16-row tile) ----
  int idxs[9][2];
#pragma unroll
  for (int rt = 0; rt < 2; ++rt) {
    const int rg = (row0 + wr * 32 + rt * 16 + l15) * 3;
    idxs[0][rt] = nbrz[rg + 0]; idxs[1][rt] = nbrz[rg + 1]; idxs[2][rt] = nbrz[rg + 2];
    idxs[3][rt] = nbrx[rg + 0]; idxs[4][rt] = nbrx[rg + 1]; idxs[5][rt] = nbrx[rg + 2];
    idxs[6][rt] = nbry[rg + 0]; idxs[7][rt] = nbry[rg + 1]; idxs[8][rt] = nbry[rg + 2];
  }
  asm volatile("s_waitcnt vmcnt(0)" ::: "memory");
  __builtin_amdgcn_sched_barrier(0);

  f4 acc0[2][4], acc1[2][4], acc2[2][4];
#pragma unroll
  for (int rt = 0; rt < 2; ++rt)
#pragma unroll
    for (int ct = 0; ct < 4; ++ct) {
      acc0[rt][ct] = f4{0.f, 0.f, 0.f, 0.f};
      acc1[rt][ct] = f4{0.f, 0.f, 0.f, 0.f};
      acc2[rt][ct] = f4{0.f, 0.f, 0.f, 0.f};
    }

  bfrag aF[2][2][4];   // [buffer][row-tile][kc] -> 64 VGPRs

  // B: 4 x 1KB fragments per wave, linear global -> linear LDS (L2-hot)
#define STAGEB(BUF, SLOT) {                                                   \
    const unsigned short* wsrc = wfrag + ((size_t)wfc[(SLOT)] << 14);         \
    _Pragma("unroll")                                                         \
    for (int i = 0; i < 4; ++i) {                                             \
      const int frag = w * 4 + i;                                             \
      __builtin_amdgcn_global_load_lds(                                       \
          (const AS1 void*)(wsrc + frag * 512 + lane * 8),                    \
          (AS3 void*)((char*)&Bb[0][0] + (BUF) * 32768 + frag * 1024),        \
          16, 0, 0);                                                          \
    } }

  // A: direct gather into MFMA fragment registers. Lane holds
  // A[row=l15][k = kc*32 + lhi*8 + e]  == 16B at fbf[idx]*256 + kc*64 + lhi*16.
#define GATHER(SET, SLOT) {                                                   \
    _Pragma("unroll")                                                         \
    for (int rt = 0; rt < 2; ++rt) {                                          \
      const char* p = (const char*)fbf +                                      \
          ((size_t)(unsigned)idxs[(SLOT)][rt] << 8) + (lhi << 4);             \
      _Pragma("unroll")                                                       \
      for (int kc = 0; kc < 4; ++kc)                                          \
        aF[(SET)][rt][kc] = *reinterpret_cast<const bfrag*>(p + kc * 64);     \
    } }

#define COMPUTE(SET, BBUF, ACCS) {                                            \
    _Pragma("unroll")                                                         \
    for (int kc = 0; kc < 4; ++kc) {                                          \
      _Pragma("unroll")                                                       \
      for (int ct = 0; ct < 4; ++ct) {                                        \
        const bfrag b = *reinterpret_cast<const bfrag*>(                      \
            (const char*)&Bb[0][0] + (BBUF) * 32768 +                         \
            (kc * 8 + wc * 4 + ct) * 1024 + lane * 16);                       \
        ACCS[0][ct] = __builtin_amdgcn_mfma_f32_16x16x32_bf16(                \
            aF[(SET)][0][kc], b, ACCS[0][ct], 0, 0, 0);                       \
        ACCS[1][ct] = __builtin_amdgcn_mfma_f32_16x16x32_bf16(                \
            aF[(SET)][1][kc], b, ACCS[1][ct], 0, 0, 0);                       \
      } } }

  // ---- prologue staging: B(0) + A(0) -> 12 outstanding ----
  STAGEB(0, 0)
  GATHER(0, 0)

  // Phase S: issue B(S+1)->buf (S+1)%3, A(S+1)->set NSET; counted wait;
  // single barrier; MFMA from buf S%3 / set SET.
#define PHASE(S, SET, NSET, ACCS, VMC) {                                      \
    if ((S) < 8) { STAGEB((S + 1) % 3, (S) + 1) GATHER(NSET, (S) + 1) }       \
    asm volatile("s_waitcnt vmcnt(" VMC ")" ::: "memory");                    \
    __builtin_amdgcn_sched_barrier(0);                                        \
    __builtin_amdgcn_s_barrier();                                             \
    __builtin_amdgcn_sched_barrier(0);                                        \
    __builtin_amdgcn_s_setprio(1);                                            \
    COMPUTE(SET, (S) % 3, ACCS)                                               \
    __builtin_amdgcn_s_setprio(0);                                            \
    __builtin_amdgcn_sched_barrier(0);                                        \
  }

  PHASE(0, 0, 1, acc0, "12")
  PHASE(1, 1, 0, acc0, "12")
  PHASE(2, 0, 1, acc0, "12")
  PHASE(3, 1, 0, acc1, "12")
  PHASE(4, 0, 1, acc1, "12")
  PHASE(5, 1, 0, acc1, "12")
  PHASE(6, 0, 1, acc2, "12")
  PHASE(7, 1, 0, acc2, "12")
  PHASE(8, 0, 1, acc2, "0")
#undef PHASE
#undef COMPUTE
#undef GATHER
#undef STAGEB

  // ---- epilogue: BN+sigmoid chains; multiply by bf16 features; store fp32 ----
#pragma unroll
  for (int ct = 0; ct < 4; ++ct) {
    const int col = wc * 64 + ct * 16 + l15;
    const float sc0 = bn[0 * CCH + col], sh0 = bn[1 * CCH + col];
    const float sc2 = bn[2 * CCH + col], sh2 = bn[3 * CCH + col];
    const float sc3 = bn[4 * CCH + col], sh3 = bn[5 * CCH + col];
#pragma unroll
    for (int rt = 0; rt < 2; ++rt)
#pragma unroll
      for (int j = 0; j < 4; ++j) {
        const int row = row0 + wr * 32 + rt * 16 + (lhi << 2) + j;
        const float az = (rt == 0) ? acc0[0][ct][j] : acc0[1][ct][j];
        const float ax = (rt == 0) ? acc1[0][ct][j] : acc1[1][ct][j];
        const float ay = (rt == 0) ? acc2[0][ct][j] : acc2[1][ct][j];
        float u = sigmoidf_(sc0 * az + sh0);
        u = sigmoidf_(sc2 * u + sh2);
        const float s3v = sigmoidf_(sc3 * ax + sh3);
        const size_t o  = ((size_t)row << 7) + col;
        out[o] = (u + ay + s3v) * bf2f(fbf[o]);
      }
  }
}

// ---------------------------------------------------------------------------
// Last-resort fallback: exact fp32
// ---------------------------------------------------------------------------
__global__ void recon_naive(const float* __restrict__ feats,
    const float* __restrict__ W1, const float* __restrict__ W2, const float* __restrict__ W3,
    const int* __restrict__ nbrz, const int* __restrict__ nbry, const int* __restrict__ nbrx,
    const float* g0, const float* b0, const float* m0, const float* v0,
    const float* g2, const float* b2, const float* m2, const float* v2,
    const float* g3, const float* b3, const float* m3, const float* v3,
    float* __restrict__ out) {
  __shared__ float rows[3][CCH];
  const int n = blockIdx.x;
  const int d = threadIdx.x;
  float res[3];
#pragma unroll
  for (int conv = 0; conv < 3; ++conv) {
    const int* nbr  = (conv == 0) ? nbrz : ((conv == 1) ? nbry : nbrx);
    const float* W  = (conv == 0) ? W1 : ((conv == 1) ? W2 : W3);
#pragma unroll
    for (int tap = 0; tap < 3; ++tap) {
      const int idx = nbr[n * 3 + tap];
      rows[tap][d] = ((unsigned)idx < (unsigned)NVOX) ? feats[((size_t)idx << 7) + d] : 0.f;
    }
    __syncthreads();
    const float* rflat = &rows[0][0];
    float s = 0.f;
    for (int k = 0; k < 3 * CCH; ++k) s += rflat[k] * W[(size_t)k * CCH + d];
    res[conv] = s;
    __syncthreads();
  }
  const float sc0 = g0[d] * rsqrtf(v0[d] + BN_EPS), sh0 = b0[d] - m0[d] * sc0;
  const float sc2 = g2[d] * rsqrtf(v2[d] + BN_EPS), sh2 = b2[d] - m2[d] * sc2;
  const float sc3 = g3[d] * rsqrtf(v3[d] + BN_EPS), sh3 = b3[d] - m3[d] * sc3;
  float u = sigmoidf_(sc0 * res[0] + sh0);
  u = sigmoidf_(sc2 * u + sh2);
  const float s3v = sigmoidf_(sc3 * res[2] + sh3);
  out[((size_t)n << 7) + d] = (u + res[1] + s3v) * feats[((size_t)n << 7) + d];
}

extern "C" void kernel_launch(void* const* d_in, const int* in_sizes, int n_in,
                              void* d_out, int out_size, void* d_ws, size_t ws_size,
                              hipStream_t stream) {
  const float* feats = (const float*)d_in[0];
  const float* W1 = (const float*)d_in[1];
  const float* W2 = (const float*)d_in[2];
  const float* W3 = (const float*)d_in[3];
  const float* g0 = (const float*)d_in[4];
  const float* b0 = (const float*)d_in[5];
  const float* m0 = (const float*)d_in[6];
  const float* v0 = (const float*)d_in[7];
  const float* g2 = (const float*)d_in[8];
  const float* b2 = (const float*)d_in[9];
  const float* m2 = (const float*)d_in[10];
  const float* v2 = (const float*)d_in[11];
  const float* g3 = (const float*)d_in[12];
  const float* b3 = (const float*)d_in[13];
  const float* m3 = (const float*)d_in[14];
  const float* v3 = (const float*)d_in[15];
  const int* nz = (const int*)d_in[16];
  const int* ny = (const int*)d_in[17];
  const int* nx = (const int*)d_in[18];
  float* out = (float*)d_out;

  const size_t wf_bytes = 288u * 1024u;                              // 294912
  const size_t bn_bytes = 4096u;                                     // 6*128*4 padded
  const size_t fb_bytes = ((size_t)NVOX + 1) * CCH * sizeof(short);  // 67.1 MB
  if (ws_size >= wf_bytes + bn_bytes + fb_bytes) {
    unsigned short* wf  = (unsigned short*)d_ws;
    float*          bnt = (float*)((char*)d_ws + wf_bytes);
    unsigned short* fbf = (unsigned short*)((char*)d_ws + wf_bytes + bn_bytes);
    hipLaunchKernelGGL(prep_wfrag, dim3(288), dim3(64), 0, stream, W1, W2, W3, wf);
    hipLaunchKernelGGL(prep_bn, dim3(1), dim3(CCH), 0, stream,
                       g0, b0, m0, v0, g2, b2, m2, v2, g3, b3, m3, v3, bnt);
    hipLaunchKernelGGL(prep_bf16, dim3((NVOX * CCH) / (256 * 8)), dim3(256), 0, stream,
                       feats, fbf);
    hipLaunchKernelGGL(recon_v4, dim3(NVOX / 128), dim3(512), 0, stream,
                       fbf, wf, bnt, nz, nx, ny, out);
  } else {
    hipLaunchKernelGGL(recon_naive, dim3(NVOX), dim3(CCH), 0, stream,
                       feats, W1, W2, W3, nz, ny, nx,
                       g0, b0, m0, v0, g2, b2, m2, v2, g3, b3, m3, v3, out);
  }
}

// Round 5
// 179.860 us; speedup vs baseline: 1.1447x; 1.1447x over previous
//
#include <hip/hip_runtime.h>
#include <hip/hip_bf16.h>
#include <stdint.h>
#include <stddef.h>

#define NVOX 262144
#define CCH 128
#define BN_EPS 1e-3f

typedef __attribute__((ext_vector_type(8))) short bfrag;   // 8 bf16 = 4 VGPRs
typedef __attribute__((ext_vector_type(4))) float f4;      // 4 f32

#define AS1 __attribute__((address_space(1)))
#define AS3 __attribute__((address_space(3)))

__device__ __forceinline__ unsigned short f2bf(float f) {
  union { float f; unsigned u; } v; v.f = f;
  unsigned r = v.u + 0x7fffu + ((v.u >> 16) & 1u);   // RNE (inputs finite)
  return (unsigned short)(r >> 16);
}

__device__ __forceinline__ bfrag pack8(f4 x, f4 y) {
  bfrag r;
  r[0] = (short)f2bf(x[0]); r[1] = (short)f2bf(x[1]);
  r[2] = (short)f2bf(x[2]); r[3] = (short)f2bf(x[3]);
  r[4] = (short)f2bf(y[0]); r[5] = (short)f2bf(y[1]);
  r[6] = (short)f2bf(y[2]); r[7] = (short)f2bf(y[3]);
  return r;
}

__device__ __forceinline__ float sigmoidf_(float x) {
  return 1.f / (1.f + __expf(-x));
}

__device__ __forceinline__ float bf2f(unsigned short h) {
  union { unsigned u; float f; } v; v.u = ((unsigned)h) << 16; return v.f;
}

// ---------------------------------------------------------------------------
// Pre-swizzle W1/W2/W3 into MFMA B-fragment order, bf16:
// region r = conv*3+tap (conv: 0=W1, 1=W2, 2=W3); frag = (r*4 + kc)*8 + tile
// lane holds B[k = kc*32 + (lane>>4)*8 + e][col = tile*16 + (lane&15)]
// ---------------------------------------------------------------------------
__global__ void prep_wfrag(const float* __restrict__ W1, const float* __restrict__ W2,
                           const float* __restrict__ W3, unsigned short* __restrict__ wf) {
  const int frag = blockIdx.x;           // 0..287
  const int tile = frag & 7;
  const int kc   = (frag >> 3) & 3;
  const int tap  = (frag >> 5) % 3;
  const int conv = frag / 96;
  const float* W = (conv == 0) ? W1 : ((conv == 1) ? W2 : W3);
  const int l   = threadIdx.x;           // 0..63
  const int col = tile * 16 + (l & 15);
  const int k0  = kc * 32 + (l >> 4) * 8;
  bfrag o;
#pragma unroll
  for (int e = 0; e < 8; ++e)
    o[e] = (short)f2bf(W[(size_t)(tap * CCH + k0 + e) * CCH + col]);
  *reinterpret_cast<bfrag*>(wf + (size_t)frag * 512 + l * 8) = o;
}

// ---------------------------------------------------------------------------
// BN scale/shift tables: bn[6][128] = {sc0, sh0, sc2, sh2, sc3, sh3}
// ---------------------------------------------------------------------------
__global__ void prep_bn(const float* g0, const float* b0, const float* m0, const float* v0,
                        const float* g2, const float* b2, const float* m2, const float* v2,
                        const float* g3, const float* b3, const float* m3, const float* v3,
                        float* __restrict__ bn) {
  const int c = threadIdx.x;
  const float s0 = g0[c] * rsqrtf(v0[c] + BN_EPS);
  const float s2 = g2[c] * rsqrtf(v2[c] + BN_EPS);
  const float s3 = g3[c] * rsqrtf(v3[c] + BN_EPS);
  bn[0 * CCH + c] = s0; bn[1 * CCH + c] = b0[c] - m0[c] * s0;
  bn[2 * CCH + c] = s2; bn[3 * CCH + c] = b2[c] - m2[c] * s2;
  bn[4 * CCH + c] = s3; bn[5 * CCH + c] = b3[c] - m3[c] * s3;
}

// ---------------------------------------------------------------------------
// Features fp32 -> bf16 (row N = zeros, the sentinel row)
// ---------------------------------------------------------------------------
__global__ void prep_bf16(const float* __restrict__ feats, unsigned short* __restrict__ fbf) {
  const size_t base = ((size_t)blockIdx.x * 256 + threadIdx.x) * 8;
  const f4 x = *reinterpret_cast<const f4*>(feats + base);
  const f4 y = *reinterpret_cast<const f4*>(feats + base + 4);
  *reinterpret_cast<bfrag*>(fbf + base) = pack8(x, y);
  if (blockIdx.x == 0 && threadIdx.x < 16) {
    bfrag z = {0, 0, 0, 0, 0, 0, 0, 0};
    *reinterpret_cast<bfrag*>(fbf + (size_t)NVOX * CCH + threadIdx.x * 8) = z;
  }
}

// ---------------------------------------------------------------------------
// v5: barrier-free main loop. Block = 1024 threads = 16 waves, each wave owns
// 16 rows x 64 cols (block: 256 rows x 64-col half). All 9 B-tiles resident in
// 144 KB LDS (single fill + ONE barrier); A gathered per-wave directly into
// MFMA fragment registers; waves run the 9 taps fully asynchronously
// (4 waves/SIMD of TLP hides scattered-gather latency tails).
// Activations folded between convs so only {run, acc} (32 f32) live.
// Slot order: conv-z(W1) 0-2, conv-x(W3) 3-5, conv-y(W2) 6-8 (y MFMAs into run).
// ---------------------------------------------------------------------------
__global__ __launch_bounds__(1024, 4)
void recon_v5(const unsigned short* __restrict__ fbf,
              const unsigned short* __restrict__ wfrag,
              const float* __restrict__ bn,
              const int* __restrict__ nbrz, const int* __restrict__ nbrx,
              const int* __restrict__ nbry,
              float* __restrict__ out) {
  __shared__ unsigned short Bb[73728];   // 144 KB: 9 slots x 16 frags x 1 KB

  const int tid  = threadIdx.x;
  const int lane = tid & 63;
  const int w    = tid >> 6;        // wave 0..15
  const int l15  = lane & 15;
  const int lhi  = lane >> 4;       // 0..3
  const int cb   = blockIdx.x & 1;  // 64-col half
  const int row0 = (blockIdx.x >> 1) * 256;
  const int wrow = row0 + w * 16;

  // W-fragment region per slot: 0-2 -> W1(z), 3-5 -> W3(x), 6-8 -> W2(y)
  constexpr int wfc[9] = {0, 1, 2, 6, 7, 8, 3, 4, 5};

  // ---- B fill: wave w copies sub-frag (kc=w>>2, ct=w&3) of all 9 slots ----
#pragma unroll
  for (int i = 0; i < 9; ++i) {
    const int g = (wfc[i] * 4 + (w >> 2)) * 8 + cb * 4 + (w & 3);  // src frag
    __builtin_amdgcn_global_load_lds(
        (const AS1 void*)(wfrag + (size_t)g * 512 + lane * 8),
        (AS3 void*)((char*)Bb + (i * 16 + w) * 1024), 16, 0, 0);
  }
  // ---- neighbor indices for this lane's row (4-lane dup across lhi) ----
  const int row = wrow + l15;
  const int rg  = row * 3;
  const int izp = nbrz[rg + 0], izn = nbrz[rg + 2];
  const int ixp = nbrx[rg + 0], ixn = nbrx[rg + 2];
  const int iyp = nbry[rg + 0], iyn = nbry[rg + 2];

  asm volatile("s_waitcnt vmcnt(0)" ::: "memory");
  __syncthreads();   // the ONLY barrier

  f4 acc[4], run[4];
#pragma unroll
  for (int ct = 0; ct < 4; ++ct) {
    acc[ct] = f4{0.f, 0.f, 0.f, 0.f};
    run[ct] = f4{0.f, 0.f, 0.f, 0.f};
  }

  bfrag aF[4];   // 16 VGPRs, single-buffered (TLP covers the load latency)

#define LOADA(IDX) {                                                          \
    const char* p = (const char*)fbf + ((size_t)(unsigned)(IDX) << 8) + (lhi << 4); \
    aF[0] = *reinterpret_cast<const bfrag*>(p);                               \
    aF[1] = *reinterpret_cast<const bfrag*>(p + 64);                          \
    aF[2] = *reinterpret_cast<const bfrag*>(p + 128);                         \
    aF[3] = *reinterpret_cast<const bfrag*>(p + 192);                         \
  }

#define TAP(SLOT, ACCS) {                                                     \
    const char* bs = (const char*)Bb + (SLOT) * 16384 + lane * 16;            \
    _Pragma("unroll")                                                         \
    for (int kc = 0; kc < 4; ++kc) {                                          \
      _Pragma("unroll")                                                       \
      for (int ct = 0; ct < 4; ++ct) {                                        \
        const bfrag b = *reinterpret_cast<const bfrag*>(                      \
            bs + (kc * 4 + ct) * 1024);                                       \
        ACCS[ct] = __builtin_amdgcn_mfma_f32_16x16x32_bf16(                   \
            aF[kc], b, ACCS[ct], 0, 0, 0);                                    \
      } } }

  // ---- conv-z (W1): prev, self, next ----
  LOADA(izp)  TAP(0, acc)
  LOADA(row)  TAP(1, acc)
  LOADA(izn)  TAP(2, acc)
  // fold: run = sigmoid(bn2(sigmoid(bn0(acc)))); acc = 0
#pragma unroll
  for (int ct = 0; ct < 4; ++ct) {
    const int col = cb * 64 + ct * 16 + l15;
    const float sc0 = bn[0 * CCH + col], sh0 = bn[1 * CCH + col];
    const float sc2 = bn[2 * CCH + col], sh2 = bn[3 * CCH + col];
#pragma unroll
    for (int j = 0; j < 4; ++j) {
      const float u = sigmoidf_(sc0 * acc[ct][j] + sh0);
      run[ct][j] = sigmoidf_(sc2 * u + sh2);
    }
    acc[ct] = f4{0.f, 0.f, 0.f, 0.f};
  }
  // ---- conv-x (W3): prev, self, next ----
  LOADA(ixp)  TAP(3, acc)
  LOADA(row)  TAP(4, acc)
  LOADA(ixn)  TAP(5, acc)
  // fold: run += sigmoid(bn3(acc))
#pragma unroll
  for (int ct = 0; ct < 4; ++ct) {
    const int col = cb * 64 + ct * 16 + l15;
    const float sc3 = bn[4 * CCH + col], sh3 = bn[5 * CCH + col];
#pragma unroll
    for (int j = 0; j < 4; ++j)
      run[ct][j] += sigmoidf_(sc3 * acc[ct][j] + sh3);
  }
  // ---- conv-y (W2): raw, MFMA directly into run ----
  LOADA(iyp)  TAP(6, run)
  LOADA(row)  TAP(7, run)
  LOADA(iyn)  TAP(8, run)

#undef TAP
#undef LOADA

  // ---- epilogue: multiply by features (bf16, L2-hot), store fp32 ----
#pragma unroll
  for (int ct = 0; ct < 4; ++ct) {
    const int col = cb * 64 + ct * 16 + l15;
#pragma unroll
    for (int j = 0; j < 4; ++j) {
      const int r = wrow + (lhi << 2) + j;
      const size_t o = ((size_t)r << 7) + col;
      out[o] = run[ct][j] * bf2f(fbf[o]);
    }
  }
}

// ---------------------------------------------------------------------------
// Last-resort fallback: exact fp32
// ---------------------------------------------------------------------------
__global__ void recon_naive(const float* __restrict__ feats,
    const float* __restrict__ W1, const float* __restrict__ W2, const float* __restrict__ W3,
    const int* __restrict__ nbrz, const int* __restrict__ nbry, const int* __restrict__ nbrx,
    const float* g0, const float* b0, const float* m0, const float* v0,
    const float* g2, const float* b2, const float* m2, const float* v2,
    const float* g3, const float* b3, const float* m3, const float* v3,
    float* __restrict__ out) {
  __shared__ float rows[3][CCH];
  const int n = blockIdx.x;
  const int d = threadIdx.x;
  float res[3];
#pragma unroll
  for (int conv = 0; conv < 3; ++conv) {
    const int* nbr  = (conv == 0) ? nbrz : ((conv == 1) ? nbry : nbrx);
    const float* W  = (conv == 0) ? W1 : ((conv == 1) ? W2 : W3);
#pragma unroll
    for (int tap = 0; tap < 3; ++tap) {
      const int idx = nbr[n * 3 + tap];
      rows[tap][d] = ((unsigned)idx < (unsigned)NVOX) ? feats[((size_t)idx << 7) + d] : 0.f;
    }
    __syncthreads();
    const float* rflat = &rows[0][0];
    float s = 0.f;
    for (int k = 0; k < 3 * CCH; ++k) s += rflat[k] * W[(size_t)k * CCH + d];
    res[conv] = s;
    __syncthreads();
  }
  const float sc0 = g0[d] * rsqrtf(v0[d] + BN_EPS), sh0 = b0[d] - m0[d] * sc0;
  const float sc2 = g2[d] * rsqrtf(v2[d] + BN_EPS), sh2 = b2[d] - m2[d] * sc2;
  const float sc3 = g3[d] * rsqrtf(v3[d] + BN_EPS), sh3 = b3[d] - m3[d] * sc3;
  float u = sigmoidf_(sc0 * res[0] + sh0);
  u = sigmoidf_(sc2 * u + sh2);
  const float s3v = sigmoidf_(sc3 * res[2] + sh3);
  out[((size_t)n << 7) + d] = (u + res[1] + s3v) * feats[((size_t)n << 7) + d];
}

extern "C" void kernel_launch(void* const* d_in, const int* in_sizes, int n_in,
                              void* d_out, int out_size, void* d_ws, size_t ws_size,
                              hipStream_t stream) {
  const float* feats = (const float*)d_in[0];
  const float* W1 = (const float*)d_in[1];
  const float* W2 = (const float*)d_in[2];
  const float* W3 = (const float*)d_in[3];
  const float* g0 = (const float*)d_in[4];
  const float* b0 = (const float*)d_in[5];
  const float* m0 = (const float*)d_in[6];
  const float* v0 = (const float*)d_in[7];
  const float* g2 = (const float*)d_in[8];
  const float* b2 = (const float*)d_in[9];
  const float* m2 = (const float*)d_in[10];
  const float* v2 = (const float*)d_in[11];
  const float* g3 = (const float*)d_in[12];
  const float* b3 = (const float*)d_in[13];
  const float* m3 = (const float*)d_in[14];
  const float* v3 = (const float*)d_in[15];
  const int* nz = (const int*)d_in[16];
  const int* ny = (const int*)d_in[17];
  const int* nx = (const int*)d_in[18];
  float* out = (float*)d_out;

  const size_t wf_bytes = 288u * 1024u;                              // 294912
  const size_t bn_bytes = 4096u;                                     // 6*128*4 padded
  const size_t fb_bytes = ((size_t)NVOX + 1) * CCH * sizeof(short);  // 67.1 MB
  if (ws_size >= wf_bytes + bn_bytes + fb_bytes) {
    unsigned short* wf  = (unsigned short*)d_ws;
    float*          bnt = (float*)((char*)d_ws + wf_bytes);
    unsigned short* fbf = (unsigned short*)((char*)d_ws + wf_bytes + bn_bytes);
    hipLaunchKernelGGL(prep_wfrag, dim3(288), dim3(64), 0, stream, W1, W2, W3, wf);
    hipLaunchKernelGGL(prep_bn, dim3(1), dim3(CCH), 0, stream,
                       g0, b0, m0, v0, g2, b2, m2, v2, g3, b3, m3, v3, bnt);
    hipLaunchKernelGGL(prep_bf16, dim3((NVOX * CCH) / (256 * 8)), dim3(256), 0, stream,
                       feats, fbf);
    hipLaunchKernelGGL(recon_v5, dim3((NVOX / 256) * 2), dim3(1024), 0, stream,
                       fbf, wf, bnt, nz, nx, ny, out);
  } else {
    hipLaunchKernelGGL(recon_naive, dim3(NVOX), dim3(CCH), 0, stream,
                       feats, W1, W2, W3, nz, ny, nx,
                       g0, b0, m0, v0, g2, b2, m2, v2, g3, b3, m3, v3, out);
  }
}